// Round 4
// baseline (220.713 us; speedup 1.0000x reference)
//
#include <hip/hip_runtime.h>
#include <cstddef>
#include <cstdint>

// z: (8, 256, 16,16,16) fp32; embedding: (1024, 256) fp32
#define CDIM 256
#define SPAT 4096
#define KCODE 1024

#define LOSS_OFF 8388608
#define PERP_OFF 8388609
#define IDX_OFF  8388610

typedef __bf16 bf16x8 __attribute__((ext_vector_type(8)));
typedef float floatx16 __attribute__((ext_vector_type(16)));
typedef unsigned short ushort8 __attribute__((ext_vector_type(8)));

__device__ __forceinline__ unsigned short f2bf_rne(float f) {
    union { float f; uint32_t u; } c; c.f = f;
    uint32_t u = c.u;
    return (unsigned short)((u + 0x7fffu + ((u >> 16) & 1u)) >> 16);
}
__device__ __forceinline__ float bf2f(unsigned short h) {
    union { float f; uint32_t u; } c; c.u = ((uint32_t)h) << 16;
    return c.f;
}

// async global->LDS, 16B per lane; lds dest = uniform base + lane*16
__device__ __forceinline__ void dma16(const void* g, void* l) {
    __builtin_amdgcn_global_load_lds(
        (const __attribute__((address_space(1))) void*)g,
        (__attribute__((address_space(3))) void*)l, 16, 0, 0);
}

// ---------------------------------------------------------------------------
// Prep: split embedding into bf16 hi/lo, stored in the BANK-SWIZZLED stage
// layout consumed by vq_main's global_load_lds staging:
//   ushort index = stage*8192 + ks*256 + phys(kb,ks)*8 + (c&7)
//   phys(kb,ks) = (((kb>>2)+ks)&7)*4 + (kb&3),  kb = c>>3, ks = code&31
// (injective in ks for fixed kb -> conflict-free A-reads; DMA is a plain
//  contiguous copy so staging itself can't conflict.)
// Also enorm (exact R1 reduction order).
// ---------------------------------------------------------------------------
__global__ __launch_bounds__(256) void vq_prep(const float* __restrict__ emb,
                                               unsigned short* __restrict__ ehsw,
                                               unsigned short* __restrict__ elsw,
                                               float* __restrict__ enorm) {
    int tid = threadIdx.x;
    int w = tid >> 6, lane = tid & 63;
    int k = blockIdx.x * 4 + w;
    const float* row = emb + (size_t)k * CDIM;
    float s = 0.0f;
#pragma unroll
    for (int i = 0; i < 4; ++i) {
        float v = row[lane + 64 * i];
        s = fmaf(v, v, s);
    }
#pragma unroll
    for (int m = 32; m > 0; m >>= 1) s += __shfl_xor(s, m, 64);
    if (lane == 0) enorm[k] = s;

    float4 v4 = *(const float4*)(row + lane * 4);
    unsigned short h0 = f2bf_rne(v4.x), h1 = f2bf_rne(v4.y),
                   h2 = f2bf_rne(v4.z), h3 = f2bf_rne(v4.w);
    ushort4 hv = make_ushort4(h0, h1, h2, h3);
    ushort4 lv = make_ushort4(f2bf_rne(v4.x - bf2f(h0)), f2bf_rne(v4.y - bf2f(h1)),
                              f2bf_rne(v4.z - bf2f(h2)), f2bf_rne(v4.w - bf2f(h3)));
    int kb = lane >> 1, cj = (lane & 1) * 4;
    int st = k >> 5, ks = k & 31;
    int phys = ((((kb >> 2) + ks) & 7) << 2) | (kb & 3);
    size_t dst = (size_t)st * 8192 + ks * 256 + phys * 8 + cj;
    *(ushort4*)(ehsw + dst) = hv;
    *(ushort4*)(elsw + dst) = lv;
}

// ---------------------------------------------------------------------------
// Main: bf16x3 MFMA distance GEMM + argmin + gather + loss + counts
// 256 blocks x 128 threads (2 waves); wave w owns cols [64w, 64w+64) of its
// block's 128 columns -> 2 N-tiles per wave, B(z) frags in registers.
// A(e) double-buffered via global_load_lds, one barrier per 32-code stage.
// d = fp32(zz+ee) - 2*M replicates np's rounding structure exactly.
// ---------------------------------------------------------------------------
__global__ __launch_bounds__(128, 1) void vq_main(const float* __restrict__ z,
                                                  const float* __restrict__ emb,
                                                  const unsigned short* __restrict__ ehsw,
                                                  const unsigned short* __restrict__ elsw,
                                                  const float* __restrict__ enorm,
                                                  float* __restrict__ counts,
                                                  float* __restrict__ losssum,
                                                  float* __restrict__ out) {
    __shared__ __align__(16) unsigned char lds[65536 + 4096 + 512 + 512];
    float* zhalf = (float*)lds;                          // phase1: 256 x 64 f32
    float* ens_s = (float*)(lds + 65536);                // 1024 f
    float* zzs   = (float*)(lds + 65536 + 4096);         // 128 f
    int*   bidxs = (int*)(lds + 65536 + 4096 + 512);     // 128 i

    const int tid = threadIdx.x;
    const int w = tid >> 6;        // wave id (uniform per wave)
    const int lane = tid & 63;
    const int m_ = lane & 31;
    const int g = lane >> 5;
    const int n0 = blockIdx.x * 128;
    const int b = n0 >> 12;
    const int sp0 = n0 & 4095;
    const float* zb = z + (size_t)b * CDIM * SPAT + sp0;

    // B-fragments: z hi/lo for 2 N-tiles, 16 kc steps (256 VGPRs, 1 wave/SIMD)
    ushort8 zh0[16], zl0[16], zh1[16], zl1[16];

    // ---- phase 1: two 64-col halves ----
    for (int h = 0; h < 2; ++h) {
        for (int i = tid; i < CDIM * 16; i += 128) {
            int c = i >> 4, seg = i & 15;
            *(float4*)&zhalf[c * 64 + seg * 4] =
                *(const float4*)(zb + (size_t)c * SPAT + h * 64 + seg * 4);
        }
        __syncthreads();
        if (w == h) {
            // extract this wave's B-fragments (cols 64w..64w+64)
#pragma unroll
            for (int t = 0; t < 2; ++t) {
#pragma unroll
                for (int kc = 0; kc < 16; ++kc) {
#pragma unroll
                    for (int j = 0; j < 8; ++j) {
                        float v = zhalf[(kc * 16 + g * 8 + j) * 64 + t * 32 + m_];
                        unsigned short hb = f2bf_rne(v);
                        unsigned short lb = f2bf_rne(v - bf2f(hb));
                        if (t == 0) { zh0[kc][j] = hb; zl0[kc][j] = lb; }
                        else        { zh1[kc][j] = hb; zl1[kc][j] = lb; }
                    }
                }
            }
        } else {
            // zz per column (R1-exact sequential fmaf order)
            float s = 0.0f;
            for (int c = 0; c < CDIM; ++c) {
                float v = zhalf[c * 64 + lane];
                s = fmaf(v, v, s);
            }
            zzs[h * 64 + lane] = s;
            if (h == 1)
                for (int i = lane; i < KCODE; i += 64) ens_s[i] = enorm[i];
        }
        __syncthreads();
    }

    const float zzv0 = zzs[w * 64 + m_];
    const float zzv1 = zzs[w * 64 + 32 + m_];

    float bs0 = 3.4e38f, bs1 = 3.4e38f;
    int bi0 = 0, bi1 = 0;

    // ---- stage-0 DMA prologue ----
    {
        const char* gh = (const char*)ehsw + ((size_t)w << 13) + (lane << 4);
        const char* gl = (const char*)elsw + ((size_t)w << 13) + (lane << 4);
        char* lh = (char*)lds + ((size_t)w << 13);
        char* ll = (char*)lds + 16384 + ((size_t)w << 13);
#pragma unroll
        for (int j = 0; j < 8; ++j) {
            dma16(gh + j * 1024, lh + j * 1024);
            dma16(gl + j * 1024, ll + j * 1024);
        }
    }

    // ---- main loop: 32 stages of 32 codes, double-buffered A ----
    for (int s = 0; s < 32; ++s) {
        __syncthreads();   // drains DMA(s); all waves done reading buf[(s+1)&1]
        if (s < 31) {
            const size_t go = ((size_t)(s + 1) << 14) + ((size_t)w << 13) + (lane << 4);
            const size_t lo = (((size_t)(s + 1) & 1) << 15) + ((size_t)w << 13);
            const char* gh = (const char*)ehsw + go;
            const char* gl = (const char*)elsw + go;
            char* lh = (char*)lds + lo;
            char* ll = (char*)lds + 16384 + lo;
#pragma unroll
            for (int j = 0; j < 8; ++j) {
                dma16(gh + j * 1024, lh + j * 1024);
                dma16(gl + j * 1024, ll + j * 1024);
            }
        }
        const unsigned short* EH = (const unsigned short*)(lds + (((size_t)s & 1) << 15));
        const unsigned short* EL = EH + 8192;

        floatx16 a0 = {0.0f, 0.0f, 0.0f, 0.0f, 0.0f, 0.0f, 0.0f, 0.0f,
                       0.0f, 0.0f, 0.0f, 0.0f, 0.0f, 0.0f, 0.0f, 0.0f};
        floatx16 a1 = a0;
#pragma unroll
        for (int kc = 0; kc < 16; ++kc) {
            int kb0 = kc * 2 + g;
            int phys = ((((kb0 >> 2) + m_) & 7) << 2) | (kb0 & 3);
            int off = m_ * 256 + phys * 8;
            bf16x8 aeh = *(const bf16x8*)&EH[off];
            bf16x8 ael = *(const bf16x8*)&EL[off];
            bf16x8 bh0 = __builtin_bit_cast(bf16x8, zh0[kc]);
            bf16x8 bl0 = __builtin_bit_cast(bf16x8, zl0[kc]);
            bf16x8 bh1 = __builtin_bit_cast(bf16x8, zh1[kc]);
            bf16x8 bl1 = __builtin_bit_cast(bf16x8, zl1[kc]);
            a0 = __builtin_amdgcn_mfma_f32_32x32x16_bf16(aeh, bh0, a0, 0, 0, 0);
            a0 = __builtin_amdgcn_mfma_f32_32x32x16_bf16(ael, bh0, a0, 0, 0, 0);
            a0 = __builtin_amdgcn_mfma_f32_32x32x16_bf16(aeh, bl0, a0, 0, 0, 0);
            a1 = __builtin_amdgcn_mfma_f32_32x32x16_bf16(aeh, bh1, a1, 0, 0, 0);
            a1 = __builtin_amdgcn_mfma_f32_32x32x16_bf16(ael, bh1, a1, 0, 0, 0);
            a1 = __builtin_amdgcn_mfma_f32_32x32x16_bf16(aeh, bl1, a1, 0, 0, 0);
        }

        // epilogue: ascending code order per lane; strict < keeps lowest idx
#pragma unroll
        for (int reg = 0; reg < 16; ++reg) {
            int mm = (reg & 3) + 8 * (reg >> 2) + 4 * g;
            int code = s * 32 + mm;
            float en = ens_s[s * 32 + mm];
            float d0 = (zzv0 + en) - 2.0f * a0[reg];
            float d1 = (zzv1 + en) - 2.0f * a1[reg];
            if (d0 < bs0) { bs0 = d0; bi0 = code; }
            if (d1 < bs1) { bs1 = d1; bi1 = code; }
        }
    }

    // ---- merge the two k-half lanes (disjoint code subsets), tie -> low ----
    {
        float s2 = __shfl_xor(bs0, 32, 64);
        int i2 = __shfl_xor(bi0, 32, 64);
        if (s2 < bs0 || (s2 == bs0 && i2 < bi0)) { bs0 = s2; bi0 = i2; }
        float s3 = __shfl_xor(bs1, 32, 64);
        int i3 = __shfl_xor(bi1, 32, 64);
        if (s3 < bs1 || (s3 == bs1 && i3 < bi1)) { bs1 = s3; bi1 = i3; }
    }
    if (lane < 32) {
        bidxs[w * 64 + m_] = bi0;
        bidxs[w * 64 + 32 + m_] = bi1;
        out[IDX_OFF + n0 + w * 64 + m_] = (float)bi0;
        out[IDX_OFF + n0 + w * 64 + 32 + m_] = (float)bi1;
        atomicAdd(&counts[bi0], 1.0f);
        atomicAdd(&counts[bi1], 1.0f);
    }
    __syncthreads();

    // ---- gather z_q, STE output zp + (q - zp), loss partial (R1-exact) ----
    float ls = 0.0f;
    float* outz = out + (size_t)b * CDIM * SPAT + sp0;
    for (int i = tid; i < CDIM * 32; i += 128) {
        int c = i >> 5, seg = i & 31;
        float4 zp = *(const float4*)(zb + (size_t)c * SPAT + seg * 4);
        int k0 = bidxs[seg * 4 + 0];
        int k1 = bidxs[seg * 4 + 1];
        int k2 = bidxs[seg * 4 + 2];
        int k3 = bidxs[seg * 4 + 3];
        float q0 = emb[(size_t)k0 * CDIM + c];
        float q1 = emb[(size_t)k1 * CDIM + c];
        float q2 = emb[(size_t)k2 * CDIM + c];
        float q3 = emb[(size_t)k3 * CDIM + c];
        float d0 = q0 - zp.x, d1 = q1 - zp.y, d2 = q2 - zp.z, d3 = q3 - zp.w;
        float4 o;
        o.x = zp.x + d0; o.y = zp.y + d1; o.z = zp.z + d2; o.w = zp.w + d3;
        ls = fmaf(d0, d0, ls); ls = fmaf(d1, d1, ls);
        ls = fmaf(d2, d2, ls); ls = fmaf(d3, d3, ls);
        *(float4*)(outz + (size_t)c * SPAT + seg * 4) = o;
    }
#pragma unroll
    for (int m = 32; m > 0; m >>= 1) ls += __shfl_xor(ls, m, 64);
    if (lane == 0) atomicAdd(losssum, ls);
}

// ---------------------------------------------------------------------------
// loss + perplexity
// ---------------------------------------------------------------------------
__global__ __launch_bounds__(256) void vq_finalize(const float* __restrict__ counts,
                                                   const float* __restrict__ losssum,
                                                   float* __restrict__ out) {
    __shared__ float red[256];
    int tid = threadIdx.x;
    float s = 0.0f;
    for (int k = tid; k < KCODE; k += 256) {
        float em = counts[k] * (1.0f / 32768.0f);
        s += em * logf(em + 1e-10f);
    }
    red[tid] = s;
    __syncthreads();
    for (int off = 128; off > 0; off >>= 1) {
        if (tid < off) red[tid] += red[tid + off];
        __syncthreads();
    }
    if (tid == 0) {
        float m = losssum[0] * (1.0f / 8388608.0f);
        out[LOSS_OFF] = m + 0.25f * m;
        out[PERP_OFF] = expf(-red[0]);
    }
}

extern "C" void kernel_launch(void* const* d_in, const int* in_sizes, int n_in,
                              void* d_out, int out_size, void* d_ws, size_t ws_size,
                              hipStream_t stream) {
    const float* z = (const float*)d_in[0];
    const float* emb = (const float*)d_in[1];
    float* out = (float*)d_out;
    unsigned short* ehsw = (unsigned short*)d_ws;            // 1024*256 ushort (swizzled)
    unsigned short* elsw = ehsw + (size_t)KCODE * CDIM;      // 1024*256 ushort
    float* enorm = (float*)(elsw + (size_t)KCODE * CDIM);    // 1024 f
    float* counts = enorm + KCODE;                           // 1024 f
    float* losssum = counts + KCODE;                         // 1 f

    hipMemsetAsync(counts, 0, (KCODE + 1) * sizeof(float), stream);
    vq_prep<<<256, 256, 0, stream>>>(emb, ehsw, elsw, enorm);
    vq_main<<<256, 128, 0, stream>>>(z, emb, ehsw, elsw, enorm, counts, losssum, out);
    vq_finalize<<<1, 256, 0, stream>>>(counts, losssum, out);
}

// Round 5
// 172.314 us; speedup vs baseline: 1.2809x; 1.2809x over previous
//
#include <hip/hip_runtime.h>
#include <cstddef>
#include <cstdint>

// z: (8, 256, 16,16,16) fp32; embedding: (1024, 256) fp32
#define CDIM 256
#define SPAT 4096
#define KCODE 1024

#define LOSS_OFF 8388608
#define PERP_OFF 8388609
#define IDX_OFF  8388610

typedef __bf16 bf16x8 __attribute__((ext_vector_type(8)));
typedef float floatx16 __attribute__((ext_vector_type(16)));
typedef unsigned short ushort8 __attribute__((ext_vector_type(8)));

__device__ __forceinline__ unsigned short f2bf_rne(float f) {
    union { float f; uint32_t u; } c; c.f = f;
    uint32_t u = c.u;
    return (unsigned short)((u + 0x7fffu + ((u >> 16) & 1u)) >> 16);
}
__device__ __forceinline__ float bf2f(unsigned short h) {
    union { float f; uint32_t u; } c; c.u = ((uint32_t)h) << 16;
    return c.f;
}

// async global->LDS, 16B per lane; lds dest = uniform base + lane*16
__device__ __forceinline__ void dma16(const void* g, void* l) {
    __builtin_amdgcn_global_load_lds(
        (const __attribute__((address_space(1))) void*)g,
        (__attribute__((address_space(3))) void*)l, 16, 0, 0);
}

// ---------------------------------------------------------------------------
// Prep: split embedding into bf16 hi/lo in the bank-swizzled stage layout:
//   ushort index = stage*8192 + ks*256 + phys*8 + (c&7)
//   phys = kb ^ (ks & 7),  kb = c>>3 (0..31), ks = code&31, stage = code>>5
// Read bank = ((kb&7)^(m&7))*4 -> all 32 banks across 8 lanes: conflict-free.
// Also enorm (exact R1 reduction order) and zero counts/losssum.
// ---------------------------------------------------------------------------
__global__ __launch_bounds__(256) void vq_prep(const float* __restrict__ emb,
                                               unsigned short* __restrict__ ehsw,
                                               unsigned short* __restrict__ elsw,
                                               float* __restrict__ enorm,
                                               float* __restrict__ counts,
                                               float* __restrict__ losssum) {
    int tid = threadIdx.x;
    if (blockIdx.x == 0) {
        for (int i = tid; i < KCODE; i += 256) counts[i] = 0.0f;
        if (tid == 0) losssum[0] = 0.0f;
    }
    int w = tid >> 6, lane = tid & 63;
    int k = blockIdx.x * 4 + w;
    const float* row = emb + (size_t)k * CDIM;
    float s = 0.0f;
#pragma unroll
    for (int i = 0; i < 4; ++i) {
        float v = row[lane + 64 * i];
        s = fmaf(v, v, s);
    }
#pragma unroll
    for (int m = 32; m > 0; m >>= 1) s += __shfl_xor(s, m, 64);
    if (lane == 0) enorm[k] = s;

    float4 v4 = *(const float4*)(row + lane * 4);
    unsigned short h0 = f2bf_rne(v4.x), h1 = f2bf_rne(v4.y),
                   h2 = f2bf_rne(v4.z), h3 = f2bf_rne(v4.w);
    ushort4 hv = make_ushort4(h0, h1, h2, h3);
    ushort4 lv = make_ushort4(f2bf_rne(v4.x - bf2f(h0)), f2bf_rne(v4.y - bf2f(h1)),
                              f2bf_rne(v4.z - bf2f(h2)), f2bf_rne(v4.w - bf2f(h3)));
    int kb = lane >> 1, cj = (lane & 1) * 4;
    int st = k >> 5, ks = k & 31;
    int phys = kb ^ (ks & 7);
    size_t dst = (size_t)st * 8192 + ks * 256 + phys * 8 + cj;
    *(ushort4*)(ehsw + dst) = hv;
    *(ushort4*)(elsw + dst) = lv;
}

// ---------------------------------------------------------------------------
// Main: bf16x3 MFMA distance GEMM + split-K argmin + gather + loss + counts
// 256 blocks x 256 threads (4 waves), 128 cols/block, 1 block/CU.
// Wave w: cols (w&1)*64 .. +64 (2 reg-resident N-tiles), codes (w>>1)*512..+512.
// 16 stages x (32 codes x 2 pairs) = 64 KB/stage, double-buffered DMA.
// d = fp32(zz+ee) - 2*M replicates np's rounding structure exactly.
// ---------------------------------------------------------------------------
__global__ __launch_bounds__(256, 1) void vq_main(const float* __restrict__ z,
                                                  const float* __restrict__ emb,
                                                  const unsigned short* __restrict__ ehsw,
                                                  const unsigned short* __restrict__ elsw,
                                                  const float* __restrict__ enorm,
                                                  float* __restrict__ counts,
                                                  float* __restrict__ losssum,
                                                  float* __restrict__ out) {
    __shared__ __align__(16) unsigned char lds[131072 + 4096 + 512 + 1024 + 1024 + 512];
    float* zhalf = (float*)lds;                       // phase1 overlay on buf0
    float* ens_s = (float*)(lds + 131072);            // 1024 f
    float* zzs   = (float*)(lds + 135168);            // 128 f
    float* pb_s  = (float*)(lds + 135680);            // [2][128]
    int*   pb_i  = (int*)(lds + 136704);              // [2][128]
    int*   bidxs = (int*)(lds + 137728);              // 128 i

    const int tid = threadIdx.x;
    const int w = tid >> 6;            // wave id
    const int lane = tid & 63;
    const int m_ = lane & 31;
    const int g = lane >> 5;
    const int kh = w >> 1;             // code-pair (0: codes 0..511, 1: 512..1023)
    const int cw = w & 1;              // column half (cols cw*64 .. +64)
    const int n0 = blockIdx.x * 128;
    const int b = n0 >> 12;
    const int sp0 = n0 & 4095;
    const float* zb = z + (size_t)b * CDIM * SPAT + sp0;

    ushort8 zh0[16], zl0[16], zh1[16], zl1[16];

    // ---- phase 1: two 64-col halves ----
    for (int h = 0; h < 2; ++h) {
        for (int i = tid; i < CDIM * 16; i += 256) {
            int c = i >> 4, seg = i & 15;
            *(float4*)&zhalf[c * 64 + seg * 4] =
                *(const float4*)(zb + (size_t)c * SPAT + h * 64 + seg * 4);
        }
        __syncthreads();
        if (cw == h) {
            // both pair-waves of this column half extract identical frags
#pragma unroll
            for (int t = 0; t < 2; ++t) {
#pragma unroll
                for (int kc = 0; kc < 16; ++kc) {
#pragma unroll
                    for (int j = 0; j < 8; ++j) {
                        float v = zhalf[(kc * 16 + g * 8 + j) * 64 + t * 32 + m_];
                        unsigned short hb = f2bf_rne(v);
                        unsigned short lb = f2bf_rne(v - bf2f(hb));
                        if (t == 0) { zh0[kc][j] = hb; zl0[kc][j] = lb; }
                        else        { zh1[kc][j] = hb; zl1[kc][j] = lb; }
                    }
                }
            }
        } else if (kh == 0) {
            // zz per column (R1-exact sequential fmaf order)
            float s = 0.0f;
            for (int c = 0; c < CDIM; ++c) {
                float v = zhalf[c * 64 + lane];
                s = fmaf(v, v, s);
            }
            zzs[h * 64 + lane] = s;
        } else if (h == 0) {
            for (int i = lane; i < KCODE; i += 64) ens_s[i] = enorm[i];
        }
        __syncthreads();
    }

    const float zzv0 = zzs[cw * 64 + m_];
    const float zzv1 = zzs[cw * 64 + 32 + m_];

    float bs0 = 3.4e38f, bs1 = 3.4e38f;
    int bi0 = 0, bi1 = 0;

    // wave's DMA source: w0 -> eh pair0, w1 -> el pair0, w2 -> eh pair1, w3 -> el pair1
    const char* gsrc = (const char*)((w & 1) ? elsw : ehsw);

    // ---- stage-0 DMA prologue (global stage kh*16) ----
    {
        const char* gp = gsrc + ((size_t)(kh * 16) << 14) + (lane << 4);
        char* lp = (char*)lds + ((size_t)w << 14);
#pragma unroll
        for (int j = 0; j < 16; ++j) dma16(gp + j * 1024, lp + j * 1024);
    }

    // ---- main loop: 16 stages, double-buffered ----
    for (int s = 0; s < 16; ++s) {
        __syncthreads();   // drains DMA(s); all waves done with buf[(s+1)&1]
        if (s < 15) {
            const char* gp = gsrc + ((size_t)(kh * 16 + s + 1) << 14) + (lane << 4);
            char* lp = (char*)lds + (((size_t)(s + 1) & 1) << 16) + ((size_t)w << 14);
#pragma unroll
            for (int j = 0; j < 16; ++j) dma16(gp + j * 1024, lp + j * 1024);
            __builtin_amdgcn_sched_barrier(0);   // keep DMA issue above compute
        }
        const char* EHb = (const char*)lds + (((size_t)s & 1) << 16) + ((size_t)kh << 15);
        const char* ELb = EHb + 16384;

        floatx16 a0 = {0.0f, 0.0f, 0.0f, 0.0f, 0.0f, 0.0f, 0.0f, 0.0f,
                       0.0f, 0.0f, 0.0f, 0.0f, 0.0f, 0.0f, 0.0f, 0.0f};
        floatx16 a1 = a0;
#pragma unroll
        for (int kc = 0; kc < 16; ++kc) {
            int kb0 = kc * 2 + g;
            int off = m_ * 512 + ((kb0 ^ (m_ & 7)) << 4);
            bf16x8 aeh = *(const bf16x8*)(EHb + off);
            bf16x8 ael = *(const bf16x8*)(ELb + off);
            bf16x8 bh0 = __builtin_bit_cast(bf16x8, zh0[kc]);
            bf16x8 bl0 = __builtin_bit_cast(bf16x8, zl0[kc]);
            bf16x8 bh1 = __builtin_bit_cast(bf16x8, zh1[kc]);
            bf16x8 bl1 = __builtin_bit_cast(bf16x8, zl1[kc]);
            a0 = __builtin_amdgcn_mfma_f32_32x32x16_bf16(aeh, bh0, a0, 0, 0, 0);
            a1 = __builtin_amdgcn_mfma_f32_32x32x16_bf16(aeh, bh1, a1, 0, 0, 0);
            a0 = __builtin_amdgcn_mfma_f32_32x32x16_bf16(ael, bh0, a0, 0, 0, 0);
            a1 = __builtin_amdgcn_mfma_f32_32x32x16_bf16(ael, bh1, a1, 0, 0, 0);
            a0 = __builtin_amdgcn_mfma_f32_32x32x16_bf16(aeh, bl0, a0, 0, 0, 0);
            a1 = __builtin_amdgcn_mfma_f32_32x32x16_bf16(aeh, bl1, a1, 0, 0, 0);
        }

        // epilogue: ascending code order per lane; strict < keeps lowest idx
#pragma unroll
        for (int reg = 0; reg < 16; ++reg) {
            int mm = (reg & 3) + 8 * (reg >> 2) + 4 * g;
            int code = kh * 512 + s * 32 + mm;
            float en = ens_s[code];
            float d0 = (zzv0 + en) - 2.0f * a0[reg];
            float d1 = (zzv1 + en) - 2.0f * a1[reg];
            if (d0 < bs0) { bs0 = d0; bi0 = code; }
            if (d1 < bs1) { bs1 = d1; bi1 = code; }
        }
    }

    // ---- merge g-halves (disjoint code subsets), tie -> low index ----
    {
        float s2 = __shfl_xor(bs0, 32, 64);
        int i2 = __shfl_xor(bi0, 32, 64);
        if (s2 < bs0 || (s2 == bs0 && i2 < bi0)) { bs0 = s2; bi0 = i2; }
        float s3 = __shfl_xor(bs1, 32, 64);
        int i3 = __shfl_xor(bi1, 32, 64);
        if (s3 < bs1 || (s3 == bs1 && i3 < bi1)) { bs1 = s3; bi1 = i3; }
    }
    __syncthreads();        // everyone done with stage buffers / ens reads
    if (lane < 32) {
        pb_s[kh * 128 + cw * 64 + m_] = bs0;
        pb_s[kh * 128 + cw * 64 + 32 + m_] = bs1;
        pb_i[kh * 128 + cw * 64 + m_] = bi0;
        pb_i[kh * 128 + cw * 64 + 32 + m_] = bi1;
    }
    __syncthreads();
    if (tid < 128) {
        float s0 = pb_s[tid], s1 = pb_s[128 + tid];
        int i0 = pb_i[tid], i1 = pb_i[128 + tid];
        // pair-0 indices always lower: tie keeps pair 0
        int ki = (s1 < s0) ? i1 : i0;
        bidxs[tid] = ki;
        out[IDX_OFF + n0 + tid] = (float)ki;
        atomicAdd(&counts[ki], 1.0f);
    }
    __syncthreads();

    // ---- gather z_q, STE output zp + (q - zp), loss (bidx cached in regs) ----
    float ls = 0.0f;
    float* outz = out + (size_t)b * CDIM * SPAT + sp0;
    const int col4 = tid & 31;         // this thread's 4 columns
    const int c_0 = tid >> 5;          // starting c, stride 8
    int k0 = bidxs[col4 * 4 + 0];
    int k1 = bidxs[col4 * 4 + 1];
    int k2 = bidxs[col4 * 4 + 2];
    int k3 = bidxs[col4 * 4 + 3];
    const float* e0 = emb + (size_t)k0 * CDIM;
    const float* e1 = emb + (size_t)k1 * CDIM;
    const float* e2 = emb + (size_t)k2 * CDIM;
    const float* e3 = emb + (size_t)k3 * CDIM;
    for (int c = c_0; c < CDIM; c += 8) {
        float4 zp = *(const float4*)(zb + (size_t)c * SPAT + col4 * 4);
        float d0 = e0[c] - zp.x, d1 = e1[c] - zp.y,
              d2 = e2[c] - zp.z, d3 = e3[c] - zp.w;
        float4 o;
        o.x = zp.x + d0; o.y = zp.y + d1; o.z = zp.z + d2; o.w = zp.w + d3;
        ls = fmaf(d0, d0, ls); ls = fmaf(d1, d1, ls);
        ls = fmaf(d2, d2, ls); ls = fmaf(d3, d3, ls);
        *(float4*)(outz + (size_t)c * SPAT + col4 * 4) = o;
    }
#pragma unroll
    for (int m = 32; m > 0; m >>= 1) ls += __shfl_xor(ls, m, 64);
    if (lane == 0) atomicAdd(losssum, ls);
}

// ---------------------------------------------------------------------------
// loss + perplexity
// ---------------------------------------------------------------------------
__global__ __launch_bounds__(256) void vq_finalize(const float* __restrict__ counts,
                                                   const float* __restrict__ losssum,
                                                   float* __restrict__ out) {
    __shared__ float red[256];
    int tid = threadIdx.x;
    float s = 0.0f;
    for (int k = tid; k < KCODE; k += 256) {
        float em = counts[k] * (1.0f / 32768.0f);
        s += em * logf(em + 1e-10f);
    }
    red[tid] = s;
    __syncthreads();
    for (int off = 128; off > 0; off >>= 1) {
        if (tid < off) red[tid] += red[tid + off];
        __syncthreads();
    }
    if (tid == 0) {
        float m = losssum[0] * (1.0f / 8388608.0f);
        out[LOSS_OFF] = m + 0.25f * m;
        out[PERP_OFF] = expf(-red[0]);
    }
}

extern "C" void kernel_launch(void* const* d_in, const int* in_sizes, int n_in,
                              void* d_out, int out_size, void* d_ws, size_t ws_size,
                              hipStream_t stream) {
    const float* z = (const float*)d_in[0];
    const float* emb = (const float*)d_in[1];
    float* out = (float*)d_out;
    unsigned short* ehsw = (unsigned short*)d_ws;            // 1024*256 ushort (swizzled)
    unsigned short* elsw = ehsw + (size_t)KCODE * CDIM;      // 1024*256 ushort
    float* enorm = (float*)(elsw + (size_t)KCODE * CDIM);    // 1024 f
    float* counts = enorm + KCODE;                           // 1024 f
    float* losssum = counts + KCODE;                         // 1 f

    vq_prep<<<256, 256, 0, stream>>>(emb, ehsw, elsw, enorm, counts, losssum);
    vq_main<<<256, 256, 0, stream>>>(z, emb, ehsw, elsw, enorm, counts, losssum, out);
    vq_finalize<<<1, 256, 0, stream>>>(counts, losssum, out);
}